// Round 11
// baseline (535.418 us; speedup 1.0000x reference)
//
#include <hip/hip_runtime.h>
#include <math.h>

#define EPSBN 1e-5f

typedef __attribute__((ext_vector_type(8))) short short8;
typedef __attribute__((ext_vector_type(8))) _Float16 f16x8;
typedef __attribute__((ext_vector_type(2))) _Float16 h2;
typedef __attribute__((ext_vector_type(4))) float f32x4;

#if defined(__has_builtin)
#if __has_builtin(__builtin_amdgcn_fdot2)
#define HAVE_FDOT2 1
#endif
#endif

__device__ __forceinline__ unsigned short f2h(float f) {
  _Float16 h = (_Float16)f;
  return __builtin_bit_cast(unsigned short, h);
}
__device__ __forceinline__ h2 bch(unsigned u) { return __builtin_bit_cast(h2, u); }
__device__ __forceinline__ unsigned h2u(h2 v) { return __builtin_bit_cast(unsigned, v); }
// LDS XOR swizzle (involution on byte bits 4-5 <- bits 7-8) -> 2 lanes/bank
__device__ __forceinline__ int swz(int b) { return b ^ (((b >> 7) & 3) << 4); }

// ---------------------------------------------------------------------------
// dual GEMM: C[M,512] = A[M,256] @ [Wl | Wr]  (f16 in, f32 acc, f16 out)
// Wt pre-transposed: Wt[n][k]. 128x128 tile, 4 waves, BK=32, f16 MFMA.
// Swapped-operand MFMA (mfma(B,A) -> D^T): ushort4 packed 8B stores.
// ---------------------------------------------------------------------------
__global__ __launch_bounds__(256) void gemm_dual(const unsigned short* __restrict__ Ab,
                                                 const unsigned short* __restrict__ Wt,
                                                 unsigned short* __restrict__ C, int M) {
  __shared__ __align__(16) short As[4096];  // 8KB [128][32] f16, swizzled
  __shared__ __align__(16) short Bs[4096];
  const int tid = threadIdx.x;
  const int lane = tid & 63, w = tid >> 6;
  const int wr = w >> 1, wc = w & 1;
  const int bm = blockIdx.x * 128, bn = blockIdx.y * 128;

  const int srow = tid >> 2;
  const int scol = (tid & 3) << 4;
  const char* gA = (const char*)Ab + (size_t)(bm + srow) * 512 + scol;
  const char* gB = (const char*)Wt + (size_t)(bn + srow) * 512 + scol;
  char* wA0 = (char*)As + swz(tid * 16);
  char* wA1 = (char*)As + swz((256 + tid) * 16);
  char* wB0 = (char*)Bs + swz(tid * 16);
  char* wB1 = (char*)Bs + swz((256 + tid) * 16);

  int aoff[4], boff[4];
#pragma unroll
  for (int i = 0; i < 4; ++i) {
    aoff[i] = swz(((wr * 64 + i * 16 + (lane & 15)) << 6) + ((lane >> 4) << 4));
    boff[i] = swz(((wc * 64 + i * 16 + (lane & 15)) << 6) + ((lane >> 4) << 4));
  }

  f32x4 acc[4][4] = {};
  short8 ra0 = *(const short8*)(gA);
  short8 ra1 = *(const short8*)(gA + 64 * 512);
  short8 rb0 = *(const short8*)(gB);
  short8 rb1 = *(const short8*)(gB + 64 * 512);

  for (int ks = 0; ks < 8; ++ks) {
    *(short8*)wA0 = ra0; *(short8*)wA1 = ra1;
    *(short8*)wB0 = rb0; *(short8*)wB1 = rb1;
    __syncthreads();
    if (ks < 7) {
      int off = (ks + 1) * 64;
      ra0 = *(const short8*)(gA + off);
      ra1 = *(const short8*)(gA + 64 * 512 + off);
      rb0 = *(const short8*)(gB + off);
      rb1 = *(const short8*)(gB + 64 * 512 + off);
    }
    short8 af[4], bfr[4];
#pragma unroll
    for (int i = 0; i < 4; ++i) af[i] = *(const short8*)((const char*)As + aoff[i]);
#pragma unroll
    for (int i = 0; i < 4; ++i) bfr[i] = *(const short8*)((const char*)Bs + boff[i]);
#pragma unroll
    for (int mr = 0; mr < 4; ++mr)
#pragma unroll
      for (int nc = 0; nc < 4; ++nc)
        acc[mr][nc] = __builtin_amdgcn_mfma_f32_16x16x32_f16(
            __builtin_bit_cast(f16x8, bfr[nc]), __builtin_bit_cast(f16x8, af[mr]),
            acc[mr][nc], 0, 0, 0);  // swapped: D^T layout
    __syncthreads();
  }

  // D^T: row = lane&15 (+m base), col = (lane>>4)*4 + j (+n base)
#pragma unroll
  for (int mr = 0; mr < 4; ++mr) {
    int row = bm + wr * 64 + mr * 16 + (lane & 15);
    if (row < M) {
#pragma unroll
      for (int nc = 0; nc < 4; ++nc) {
        int col = bn + wc * 64 + nc * 16 + ((lane >> 4) << 2);
        ushort4 o;
        o.x = f2h(acc[mr][nc][0]); o.y = f2h(acc[mr][nc][1]);
        o.z = f2h(acc[mr][nc][2]); o.w = f2h(acc[mr][nc][3]);
        *(ushort4*)&C[(size_t)row * 512 + col] = o;
      }
    }
  }
}

// ---------------------------------------------------------------------------
// prep: f32->f16 convert of x, Wt1/Wt2 build (transpose+cvt), dst histogram
// ---------------------------------------------------------------------------
__global__ void prep(const float* __restrict__ x, const float* __restrict__ W1l,
                     const float* __restrict__ W1r, const float* __restrict__ W2l,
                     const float* __restrict__ W2r, const int* __restrict__ ei,
                     unsigned short* __restrict__ xh, unsigned short* __restrict__ Wt1,
                     unsigned short* __restrict__ Wt2, int* __restrict__ cnt,
                     int n4x, int Etot, int E) {
  int t = blockIdx.x * 256 + threadIdx.x;
  if (t < n4x) {
    float4 v = *(const float4*)&x[(size_t)t * 4];
    ushort4 o;
    o.x = f2h(v.x); o.y = f2h(v.y); o.z = f2h(v.z); o.w = f2h(v.w);
    *(ushort4*)&xh[(size_t)t * 4] = o;
    return;
  }
  t -= n4x;
  if (t < 131072) {
    int n = t >> 8, k = t & 255;
    const float* W = (n < 256) ? W1l : W1r;
    Wt1[t] = f2h(W[k * 256 + (n & 255)]);
    return;
  }
  t -= 131072;
  if (t < 131072) {
    int n = t >> 8, k = t & 255;
    const float* W = (n < 256) ? W2l : W2r;
    Wt2[t] = f2h(W[k * 256 + (n & 255)]);
    return;
  }
  t -= 131072;
  if (t < Etot) {
    int d = (t < E) ? ei[E + t] : t - E;
    atomicAdd(&cnt[d], 1);
  }
}

// ---------------------------------------------------------------------------
// hierarchical exclusive scan of cnt[N] -> rowptr[N]
// ---------------------------------------------------------------------------
__global__ __launch_bounds__(256) void scan_partial(const int* __restrict__ cnt,
                                                    int* __restrict__ bsum, int N) {
  __shared__ int red[256];
  int t = threadIdx.x;
  int i = blockIdx.x * 1024 + t * 4;
  int s = 0;
  if (i + 3 < N) {
    int4 v = *(const int4*)&cnt[i];
    s = v.x + v.y + v.z + v.w;
  } else {
    for (int k = 0; k < 4; ++k)
      if (i + k < N) s += cnt[i + k];
  }
  red[t] = s;
  __syncthreads();
  for (int off = 128; off > 0; off >>= 1) {
    if (t < off) red[t] += red[t + off];
    __syncthreads();
  }
  if (t == 0) bsum[blockIdx.x] = red[0];
}

__global__ void scan_bsums(const int* __restrict__ bsum, int* __restrict__ boff,
                           int* __restrict__ rowptr, int nb, int N, int Etot) {
  int t = threadIdx.x;  // 64
  int v = (t < nb) ? bsum[t] : 0;
  int x = v;
  for (int off = 1; off < 64; off <<= 1) {
    int y = __shfl_up(x, off);
    if (t >= off) x += y;
  }
  if (t < nb) boff[t] = x - v;  // exclusive
  if (t == 0) rowptr[N] = Etot;
}

__global__ __launch_bounds__(256) void scan_final(int* __restrict__ cnt,
                                                  const int* __restrict__ boff,
                                                  int* __restrict__ rowptr, int N) {
  __shared__ int red[256];
  int t = threadIdx.x;
  int i = blockIdx.x * 1024 + t * 4;
  int c0 = 0, c1 = 0, c2 = 0, c3 = 0;
  if (i + 3 < N) {
    int4 v = *(const int4*)&cnt[i];
    c0 = v.x; c1 = v.y; c2 = v.z; c3 = v.w;
    *(int4*)&cnt[i] = make_int4(0, 0, 0, 0);  // reset for scatter pass
  } else {
    if (i + 0 < N) { c0 = cnt[i + 0]; cnt[i + 0] = 0; }
    if (i + 1 < N) { c1 = cnt[i + 1]; cnt[i + 1] = 0; }
    if (i + 2 < N) { c2 = cnt[i + 2]; cnt[i + 2] = 0; }
    if (i + 3 < N) { c3 = cnt[i + 3]; cnt[i + 3] = 0; }
  }
  int s = c0 + c1 + c2 + c3;
  red[t] = s;
  __syncthreads();
  for (int off = 1; off < 256; off <<= 1) {
    int y = (t >= off) ? red[t - off] : 0;
    __syncthreads();
    red[t] += y;
    __syncthreads();
  }
  int excl = red[t] - s + boff[blockIdx.x];
  if (i + 3 < N) {
    *(int4*)&rowptr[i] = make_int4(excl, excl + c0, excl + c0 + c1, excl + c0 + c1 + c2);
  } else {
    if (i + 0 < N) rowptr[i + 0] = excl;
    if (i + 1 < N) rowptr[i + 1] = excl + c0;
    if (i + 2 < N) rowptr[i + 2] = excl + c0 + c1;
    if (i + 3 < N) rowptr[i + 3] = excl + c0 + c1 + c2;
  }
}

__global__ void scatter_src(const int* __restrict__ ei, const int* __restrict__ rowptr,
                            int* __restrict__ cur, int* __restrict__ srcs,
                            int Etot, int E) {
  int e = blockIdx.x * 256 + threadIdx.x;
  if (e >= Etot) return;
  int s, d;
  if (e < E) { s = ei[e]; d = ei[E + e]; } else { s = e - E; d = s; }
  int pos = rowptr[d] + atomicAdd(&cur[d], 1);
  srcs[pos] = s;
}

// ---------------------------------------------------------------------------
// Fused GATv2: one wave per dst, 2 edges/iteration (32 lanes each), raw-exp
// softmax, 16B/lane f16 gathers, 2-iter (4-edge) prefetch pipeline.
// lane = half*32+sub; sub owns ch sub*8..+7 (head = sub>>3, 8 lanes/head).
// leaky_relu(x) = 0.6x + 0.4|x|;  score = e.(0.6w) + |e|.(0.4w)
// ---------------------------------------------------------------------------
template <int CONCAT>
__global__ __launch_bounds__(256) void gat_fused(const unsigned short* __restrict__ xlr,
                                                 const float* __restrict__ att,
                                                 const float* __restrict__ bias,
                                                 const int* __restrict__ rowptr,
                                                 const int* __restrict__ srcs,
                                                 void* __restrict__ outv, int N) {
  int d = (blockIdx.x << 2) + (threadIdx.x >> 6);
  if (d >= N) return;
  int lane = threadIdx.x & 63;
  int half = lane >> 5, sub = lane & 31;
  uint4 ub = *(const uint4*)&xlr[(size_t)d * 512 + 256 + sub * 8];
  h2 xb0 = bch(ub.x), xb1 = bch(ub.y), xb2 = bch(ub.z), xb3 = bch(ub.w);
  float4 wa = *(const float4*)&att[sub * 8];
  float4 wb = *(const float4*)&att[sub * 8 + 4];
  h2 w060 = {(_Float16)(0.6f * wa.x), (_Float16)(0.6f * wa.y)};
  h2 w061 = {(_Float16)(0.6f * wa.z), (_Float16)(0.6f * wa.w)};
  h2 w062 = {(_Float16)(0.6f * wb.x), (_Float16)(0.6f * wb.y)};
  h2 w063 = {(_Float16)(0.6f * wb.z), (_Float16)(0.6f * wb.w)};
  h2 w040 = {(_Float16)(0.4f * wa.x), (_Float16)(0.4f * wa.y)};
  h2 w041 = {(_Float16)(0.4f * wa.z), (_Float16)(0.4f * wa.w)};
  h2 w042 = {(_Float16)(0.4f * wb.x), (_Float16)(0.4f * wb.y)};
  h2 w043 = {(_Float16)(0.4f * wb.z), (_Float16)(0.4f * wb.w)};
  int i0 = rowptr[d], end = rowptr[d + 1];
  int eM1 = end - 1;
  float den = 0.f;
  float acc[8] = {};

  auto GLD = [&](int e) -> uint4 {
    int j = min(e + half, eM1);
    return *(const uint4*)&xlr[(size_t)srcs[j] * 512 + sub * 8];
  };
  uint4 bufA = GLD(i0), bufB = GLD(i0 + 2);
  for (int i = i0; i < end; i += 2) {
    uint4 c = bufA;
    bufA = bufB;
    bufB = GLD(i + 4);
    h2 c0 = bch(c.x), c1 = bch(c.y), c2 = bch(c.z), c3 = bch(c.w);
    h2 e0 = c0 + xb0, e1 = c1 + xb1, e2 = c2 + xb2, e3 = c3 + xb3;
    float p;
#ifdef HAVE_FDOT2
    h2 a0 = bch(h2u(e0) & 0x7FFF7FFFu);
    h2 a1 = bch(h2u(e1) & 0x7FFF7FFFu);
    h2 a2 = bch(h2u(e2) & 0x7FFF7FFFu);
    h2 a3 = bch(h2u(e3) & 0x7FFF7FFFu);
    p = __builtin_amdgcn_fdot2(a0, w040,
        __builtin_amdgcn_fdot2(a1, w041,
        __builtin_amdgcn_fdot2(a2, w042,
        __builtin_amdgcn_fdot2(a3, w043,
        __builtin_amdgcn_fdot2(e0, w060,
        __builtin_amdgcn_fdot2(e1, w061,
        __builtin_amdgcn_fdot2(e2, w062,
        __builtin_amdgcn_fdot2(e3, w063, 0.f, false), false), false), false),
        false), false), false), false);
#else
    {
      float f0 = (float)e0.x, f1 = (float)e0.y, f2 = (float)e1.x, f3 = (float)e1.y;
      float f4 = (float)e2.x, f5 = (float)e2.y, f6 = (float)e3.x, f7 = (float)e3.y;
      float l0 = fmaxf(f0, 0.2f * f0), l1 = fmaxf(f1, 0.2f * f1);
      float l2 = fmaxf(f2, 0.2f * f2), l3 = fmaxf(f3, 0.2f * f3);
      float l4 = fmaxf(f4, 0.2f * f4), l5 = fmaxf(f5, 0.2f * f5);
      float l6 = fmaxf(f6, 0.2f * f6), l7 = fmaxf(f7, 0.2f * f7);
      p = l0 * wa.x + l1 * wa.y + l2 * wa.z + l3 * wa.w +
          l4 * wb.x + l5 * wb.y + l6 * wb.z + l7 * wb.w;
    }
#endif
    p += __shfl_xor(p, 1);
    p += __shfl_xor(p, 2);
    p += __shfl_xor(p, 4);   // all 8 lanes of the head group hold the score
    bool valid = (i + half) < end;
    float ex = valid ? __expf(p) : 0.f;
    den += ex;
    acc[0] = fmaf(ex, (float)c0.x, acc[0]);
    acc[1] = fmaf(ex, (float)c0.y, acc[1]);
    acc[2] = fmaf(ex, (float)c1.x, acc[2]);
    acc[3] = fmaf(ex, (float)c1.y, acc[3]);
    acc[4] = fmaf(ex, (float)c2.x, acc[4]);
    acc[5] = fmaf(ex, (float)c2.y, acc[5]);
    acc[6] = fmaf(ex, (float)c3.x, acc[6]);
    acc[7] = fmaf(ex, (float)c3.y, acc[7]);
  }
  // merge the two edge-halves
  den += __shfl_xor(den, 32);
#pragma unroll
  for (int k = 0; k < 8; ++k) acc[k] += __shfl_xor(acc[k], 32);
  float inv = 1.f / den;
  if (CONCAT) {
    if (half == 0) {
      float4 ba = *(const float4*)&bias[sub * 8];
      float4 bb2 = *(const float4*)&bias[sub * 8 + 4];
      uint4 o;
      o.x = (unsigned)f2h(fmaf(acc[0], inv, ba.x)) | ((unsigned)f2h(fmaf(acc[1], inv, ba.y)) << 16);
      o.y = (unsigned)f2h(fmaf(acc[2], inv, ba.z)) | ((unsigned)f2h(fmaf(acc[3], inv, ba.w)) << 16);
      o.z = (unsigned)f2h(fmaf(acc[4], inv, bb2.x)) | ((unsigned)f2h(fmaf(acc[5], inv, bb2.y)) << 16);
      o.w = (unsigned)f2h(fmaf(acc[6], inv, bb2.z)) | ((unsigned)f2h(fmaf(acc[7], inv, bb2.w)) << 16);
      *(uint4*)&((unsigned short*)outv)[(size_t)d * 256 + sub * 8] = o;
    }
  } else {
    float v[8];
#pragma unroll
    for (int k = 0; k < 8; ++k) {
      v[k] = acc[k] * inv;
      v[k] += __shfl_xor(v[k], 8);
      v[k] += __shfl_xor(v[k], 16);  // sum over 4 heads
    }
    if (lane < 8) {  // half==0 && sub<8: ch sub*8..+7 of 64
      float4 ba = *(const float4*)&bias[sub * 8];
      float4 bb2 = *(const float4*)&bias[sub * 8 + 4];
      float* op = &((float*)outv)[(size_t)d * 64 + sub * 8];
      *(float4*)op = make_float4(0.25f * v[0] + ba.x, 0.25f * v[1] + ba.y,
                                 0.25f * v[2] + ba.z, 0.25f * v[3] + ba.w);
      *(float4*)(op + 4) = make_float4(0.25f * v[4] + bb2.x, 0.25f * v[5] + bb2.y,
                                       0.25f * v[6] + bb2.z, 0.25f * v[7] + bb2.w);
    }
  }
}

// column sums/sumsq over h[N,256] f16, LDS-reduced, 8 atomics per 64 lanes
__global__ __launch_bounds__(256) void bn_stats(const unsigned short* __restrict__ h,
                                                float* __restrict__ sums, int N) {
  __shared__ float4 rs[4][64], rq[4][64];
  int lane = threadIdx.x & 63;
  int rg = threadIdx.x >> 6;
  int c4 = lane * 4;
  float s0 = 0, s1 = 0, s2 = 0, s3 = 0, q0 = 0, q1 = 0, q2 = 0, q3 = 0;
  for (int r = blockIdx.x * 4 + rg; r < N; r += gridDim.x * 4) {
    uint2 v = *(const uint2*)&h[(size_t)r * 256 + c4];
    h2 a = bch(v.x), b = bch(v.y);
    float f0 = (float)a.x, f1 = (float)a.y, f2 = (float)b.x, f3 = (float)b.y;
    s0 += f0; q0 += f0 * f0;
    s1 += f1; q1 += f1 * f1;
    s2 += f2; q2 += f2 * f2;
    s3 += f3; q3 += f3 * f3;
  }
  rs[rg][lane] = make_float4(s0, s1, s2, s3);
  rq[rg][lane] = make_float4(q0, q1, q2, q3);
  __syncthreads();
  if (rg == 0) {
    float4 S = rs[0][lane], Q = rq[0][lane];
#pragma unroll
    for (int g = 1; g < 4; ++g) {
      float4 t = rs[g][lane]; S.x += t.x; S.y += t.y; S.z += t.z; S.w += t.w;
      float4 u = rq[g][lane]; Q.x += u.x; Q.y += u.y; Q.z += u.z; Q.w += u.w;
    }
    atomicAdd(&sums[c4 + 0], S.x); atomicAdd(&sums[c4 + 1], S.y);
    atomicAdd(&sums[c4 + 2], S.z); atomicAdd(&sums[c4 + 3], S.w);
    atomicAdd(&sums[256 + c4 + 0], Q.x); atomicAdd(&sums[256 + c4 + 1], Q.y);
    atomicAdd(&sums[256 + c4 + 2], Q.z); atomicAdd(&sums[256 + c4 + 3], Q.w);
  }
}

// h = relu(h*scale+shift), f16 in-place, 8 elems/thread; coef computed inline
__global__ void bn_apply_relu(unsigned short* __restrict__ h, const float* __restrict__ sums,
                              const float* __restrict__ g, const float* __restrict__ be,
                              int N) {
  int i = blockIdx.x * 256 + threadIdx.x;
  if (i >= N * 32) return;
  int base = i * 8, c = base & 255;
  float inv_n = 1.f / (float)N;
  float4 sm0 = *(const float4*)&sums[c],      sm1 = *(const float4*)&sums[c + 4];
  float4 qm0 = *(const float4*)&sums[256 + c], qm1 = *(const float4*)&sums[256 + c + 4];
  float4 gg0 = *(const float4*)&g[c],  gg1 = *(const float4*)&g[c + 4];
  float4 bb0 = *(const float4*)&be[c], bb1 = *(const float4*)&be[c + 4];
  float sc[8], sh[8];
  float mus[8] = {sm0.x * inv_n, sm0.y * inv_n, sm0.z * inv_n, sm0.w * inv_n,
                  sm1.x * inv_n, sm1.y * inv_n, sm1.z * inv_n, sm1.w * inv_n};
  float qs[8] = {qm0.x * inv_n, qm0.y * inv_n, qm0.z * inv_n, qm0.w * inv_n,
                 qm1.x * inv_n, qm1.y * inv_n, qm1.z * inv_n, qm1.w * inv_n};
  float gv[8] = {gg0.x, gg0.y, gg0.z, gg0.w, gg1.x, gg1.y, gg1.z, gg1.w};
  float bv[8] = {bb0.x, bb0.y, bb0.z, bb0.w, bb1.x, bb1.y, bb1.z, bb1.w};
#pragma unroll
  for (int k = 0; k < 8; ++k) {
    sc[k] = gv[k] * rsqrtf(qs[k] - mus[k] * mus[k] + EPSBN);
    sh[k] = bv[k] - mus[k] * sc[k];
  }
  uint4 v = *(const uint4*)&h[base];
  h2 p0 = bch(v.x), p1 = bch(v.y), p2 = bch(v.z), p3 = bch(v.w);
  float r[8];
  r[0] = fmaf((float)p0.x, sc[0], sh[0]);
  r[1] = fmaf((float)p0.y, sc[1], sh[1]);
  r[2] = fmaf((float)p1.x, sc[2], sh[2]);
  r[3] = fmaf((float)p1.y, sc[3], sh[3]);
  r[4] = fmaf((float)p2.x, sc[4], sh[4]);
  r[5] = fmaf((float)p2.y, sc[5], sh[5]);
  r[6] = fmaf((float)p3.x, sc[6], sh[6]);
  r[7] = fmaf((float)p3.y, sc[7], sh[7]);
#pragma unroll
  for (int k = 0; k < 8; ++k) r[k] = r[k] > 0.f ? r[k] : 0.f;
  uint4 o;
  o.x = (unsigned)f2h(r[0]) | ((unsigned)f2h(r[1]) << 16);
  o.y = (unsigned)f2h(r[2]) | ((unsigned)f2h(r[3]) << 16);
  o.z = (unsigned)f2h(r[4]) | ((unsigned)f2h(r[5]) << 16);
  o.w = (unsigned)f2h(r[6]) | ((unsigned)f2h(r[7]) << 16);
  *(uint4*)&h[base] = o;
}

// column stats over o[:, :32], coalesced float4 reads + LDS reduce
__global__ __launch_bounds__(256) void bn2_stats(const float* __restrict__ o,
                                                 float* __restrict__ sums, int N) {
  __shared__ float4 lsum[256], lqum[256];
  int t = threadIdx.x;
  int q = t & 7, rs = t >> 3;  // colquad 0..7, row-slot 0..31
  float4 S = {0, 0, 0, 0}, Q = {0, 0, 0, 0};
  for (int r = blockIdx.x * 32 + rs; r < N; r += gridDim.x * 32) {
    float4 v = *(const float4*)&o[(size_t)r * 64 + q * 4];
    S.x += v.x; Q.x += v.x * v.x;
    S.y += v.y; Q.y += v.y * v.y;
    S.z += v.z; Q.z += v.z * v.z;
    S.w += v.w; Q.w += v.w * v.w;
  }
  lsum[t] = S; lqum[t] = Q;
  __syncthreads();
  if (t < 8) {
    float4 Sa = lsum[t], Qa = lqum[t];
    for (int k = 1; k < 32; ++k) {
      float4 a = lsum[t + 8 * k], b = lqum[t + 8 * k];
      Sa.x += a.x; Sa.y += a.y; Sa.z += a.z; Sa.w += a.w;
      Qa.x += b.x; Qa.y += b.y; Qa.z += b.z; Qa.w += b.w;
    }
    atomicAdd(&sums[t * 4 + 0], Sa.x); atomicAdd(&sums[t * 4 + 1], Sa.y);
    atomicAdd(&sums[t * 4 + 2], Sa.z); atomicAdd(&sums[t * 4 + 3], Sa.w);
    atomicAdd(&sums[32 + t * 4 + 0], Qa.x); atomicAdd(&sums[32 + t * 4 + 1], Qa.y);
    atomicAdd(&sums[32 + t * 4 + 2], Qa.z); atomicAdd(&sums[32 + t * 4 + 3], Qa.w);
  }
}

// row-parallel: lanes 0-31 -> z_mu, lanes 32-63 -> sigmoid. Coalesced reads.
__global__ void write_out(const float* __restrict__ o, const float* __restrict__ sums,
                          float* __restrict__ out, int N) {
  int t = threadIdx.x;
  int n = blockIdx.x * 4 + (t >> 6);
  if (n >= N) return;
  int lane = t & 63;
  float v = o[(size_t)n * 64 + lane];
  if (lane < 32) {
    float inv_n = 1.f / (float)N;
    float mu = sums[lane] * inv_n;
    float var = sums[32 + lane] * inv_n - mu * mu;
    out[(size_t)n * 32 + lane] = (v - mu) * rsqrtf(var + EPSBN);
  } else {
    out[(size_t)N * 32 + (size_t)n * 32 + (lane - 32)] = 1.f / (1.f + __expf(-v));
  }
}

extern "C" void kernel_launch(void* const* d_in, const int* in_sizes, int n_in,
                              void* d_out, int out_size, void* d_ws, size_t ws_size,
                              hipStream_t stream) {
  const float* x    = (const float*)d_in[0];
  const int*   ei   = (const int*)d_in[1];
  const float* W1l  = (const float*)d_in[2];
  const float* W1r  = (const float*)d_in[3];
  const float* att1 = (const float*)d_in[4];
  const float* b1   = (const float*)d_in[5];
  const float* g1   = (const float*)d_in[6];
  const float* be1  = (const float*)d_in[7];
  const float* W2l  = (const float*)d_in[8];
  const float* W2r  = (const float*)d_in[9];
  const float* att2 = (const float*)d_in[10];
  const float* b2   = (const float*)d_in[11];
  float* out = (float*)d_out;

  const int N = in_sizes[0] / 256;   // 50000
  const int E = in_sizes[1] / 2;     // 800000
  const int Etot = E + N;
  const int Npad = ((N + 127) / 128) * 128;
  const int nb = (N + 1023) / 1024;  // scan chunks

  char* ws = (char*)d_ws;
  unsigned short* xh  = (unsigned short*)ws; ws += (size_t)Npad * 256 * 2;  // x f16
  unsigned short* hb  = (unsigned short*)ws; ws += (size_t)Npad * 256 * 2;  // h1 f16
  unsigned short* AB  = (unsigned short*)ws; ws += (size_t)Npad * 512 * 2;  // [xl|xr] f16
  unsigned short* Wt1 = (unsigned short*)ws; ws += (size_t)512 * 256 * 2;
  unsigned short* Wt2 = (unsigned short*)ws; ws += (size_t)512 * 256 * 2;
  float* o    = (float*)ws;  ws += (size_t)N * 64 * 4;
  int* rowptr = (int*)ws;    ws += (size_t)(N + 1) * 4;
  int* cnt    = (int*)ws;    ws += (size_t)N * 4;
  int* srcs   = (int*)ws;    ws += (size_t)Etot * 4;
  int* bsum   = (int*)ws;    ws += 64 * 4;
  int* boff   = (int*)ws;    ws += 64 * 4;
  float* sums1 = (float*)ws; ws += 512 * 4;
  float* sums2 = (float*)ws; ws += 64 * 4;

  dim3 gemmGrid(Npad / 128, 4);
  int dstBlocks = (N + 3) / 4;
  int n4x = N * 64;
  int prepTotal = n4x + 131072 + 131072 + Etot;

  hipMemsetAsync(cnt, 0, (size_t)N * 4, stream);
  hipMemsetAsync(sums1, 0, 512 * 4, stream);
  hipMemsetAsync(sums2, 0, 64 * 4, stream);
  prep<<<(prepTotal + 255) / 256, 256, 0, stream>>>(x, W1l, W1r, W2l, W2r, ei,
                                                    xh, Wt1, Wt2, cnt, n4x, Etot, E);
  scan_partial<<<nb, 256, 0, stream>>>(cnt, bsum, N);
  scan_bsums<<<1, 64, 0, stream>>>(bsum, boff, rowptr, nb, N, Etot);
  scan_final<<<nb, 256, 0, stream>>>(cnt, boff, rowptr, N);  // also zeroes cnt
  scatter_src<<<(Etot + 255) / 256, 256, 0, stream>>>(ei, rowptr, cnt, srcs, Etot, E);

  // ---- conv1 ----
  gemm_dual<<<gemmGrid, 256, 0, stream>>>(xh, Wt1, AB, N);
  gat_fused<1><<<dstBlocks, 256, 0, stream>>>(AB, att1, b1, rowptr, srcs, hb, N);
  bn_stats<<<512, 256, 0, stream>>>(hb, sums1, N);
  bn_apply_relu<<<(N * 32 + 255) / 256, 256, 0, stream>>>(hb, sums1, g1, be1, N);

  // ---- conv2 ----
  gemm_dual<<<gemmGrid, 256, 0, stream>>>(hb, Wt2, AB, N);
  gat_fused<0><<<dstBlocks, 256, 0, stream>>>(AB, att2, b2, rowptr, srcs, o, N);
  bn2_stats<<<128, 256, 0, stream>>>(o, sums2, N);
  write_out<<<dstBlocks, 256, 0, stream>>>(o, sums2, out, N);
}

// Round 12
// 509.952 us; speedup vs baseline: 1.0499x; 1.0499x over previous
//
#include <hip/hip_runtime.h>
#include <math.h>

#define EPSBN 1e-5f

typedef __attribute__((ext_vector_type(8))) short short8;
typedef __attribute__((ext_vector_type(8))) _Float16 f16x8;
typedef __attribute__((ext_vector_type(2))) _Float16 h2;
typedef __attribute__((ext_vector_type(4))) float f32x4;

#if defined(__has_builtin)
#if __has_builtin(__builtin_amdgcn_fdot2)
#define HAVE_FDOT2 1
#endif
#endif

__device__ __forceinline__ unsigned short f2h(float f) {
  _Float16 h = (_Float16)f;
  return __builtin_bit_cast(unsigned short, h);
}
__device__ __forceinline__ h2 bch(unsigned u) { return __builtin_bit_cast(h2, u); }
__device__ __forceinline__ unsigned h2u(h2 v) { return __builtin_bit_cast(unsigned, v); }
// LDS XOR swizzle (involution on byte bits 4-5 <- bits 7-8) -> 2 lanes/bank
__device__ __forceinline__ int swz(int b) { return b ^ (((b >> 7) & 3) << 4); }

// ---------------------------------------------------------------------------
// dual GEMM: C[M,512] = A[M,256] @ [Wl | Wr]  (f16 in, f32 acc, f16 out)
// Wt pre-transposed: Wt[n][k]. 128x128 tile, 4 waves, BK=32, f16 MFMA.
// Swapped-operand MFMA (mfma(B,A) -> D^T): ushort4 packed 8B stores.
// ---------------------------------------------------------------------------
__global__ __launch_bounds__(256) void gemm_dual(const unsigned short* __restrict__ Ab,
                                                 const unsigned short* __restrict__ Wt,
                                                 unsigned short* __restrict__ C, int M) {
  __shared__ __align__(16) short As[4096];  // 8KB [128][32] f16, swizzled
  __shared__ __align__(16) short Bs[4096];
  const int tid = threadIdx.x;
  const int lane = tid & 63, w = tid >> 6;
  const int wr = w >> 1, wc = w & 1;
  const int bm = blockIdx.x * 128, bn = blockIdx.y * 128;

  const int srow = tid >> 2;
  const int scol = (tid & 3) << 4;
  const char* gA = (const char*)Ab + (size_t)(bm + srow) * 512 + scol;
  const char* gB = (const char*)Wt + (size_t)(bn + srow) * 512 + scol;
  char* wA0 = (char*)As + swz(tid * 16);
  char* wA1 = (char*)As + swz((256 + tid) * 16);
  char* wB0 = (char*)Bs + swz(tid * 16);
  char* wB1 = (char*)Bs + swz((256 + tid) * 16);

  int aoff[4], boff[4];
#pragma unroll
  for (int i = 0; i < 4; ++i) {
    aoff[i] = swz(((wr * 64 + i * 16 + (lane & 15)) << 6) + ((lane >> 4) << 4));
    boff[i] = swz(((wc * 64 + i * 16 + (lane & 15)) << 6) + ((lane >> 4) << 4));
  }

  f32x4 acc[4][4] = {};
  short8 ra0 = *(const short8*)(gA);
  short8 ra1 = *(const short8*)(gA + 64 * 512);
  short8 rb0 = *(const short8*)(gB);
  short8 rb1 = *(const short8*)(gB + 64 * 512);

  for (int ks = 0; ks < 8; ++ks) {
    *(short8*)wA0 = ra0; *(short8*)wA1 = ra1;
    *(short8*)wB0 = rb0; *(short8*)wB1 = rb1;
    __syncthreads();
    if (ks < 7) {
      int off = (ks + 1) * 64;
      ra0 = *(const short8*)(gA + off);
      ra1 = *(const short8*)(gA + 64 * 512 + off);
      rb0 = *(const short8*)(gB + off);
      rb1 = *(const short8*)(gB + 64 * 512 + off);
    }
    short8 af[4], bfr[4];
#pragma unroll
    for (int i = 0; i < 4; ++i) af[i] = *(const short8*)((const char*)As + aoff[i]);
#pragma unroll
    for (int i = 0; i < 4; ++i) bfr[i] = *(const short8*)((const char*)Bs + boff[i]);
#pragma unroll
    for (int mr = 0; mr < 4; ++mr)
#pragma unroll
      for (int nc = 0; nc < 4; ++nc)
        acc[mr][nc] = __builtin_amdgcn_mfma_f32_16x16x32_f16(
            __builtin_bit_cast(f16x8, bfr[nc]), __builtin_bit_cast(f16x8, af[mr]),
            acc[mr][nc], 0, 0, 0);  // swapped: D^T layout
    __syncthreads();
  }

  // D^T: row = lane&15 (+m base), col = (lane>>4)*4 + j (+n base)
#pragma unroll
  for (int mr = 0; mr < 4; ++mr) {
    int row = bm + wr * 64 + mr * 16 + (lane & 15);
    if (row < M) {
#pragma unroll
      for (int nc = 0; nc < 4; ++nc) {
        int col = bn + wc * 64 + nc * 16 + ((lane >> 4) << 2);
        ushort4 o;
        o.x = f2h(acc[mr][nc][0]); o.y = f2h(acc[mr][nc][1]);
        o.z = f2h(acc[mr][nc][2]); o.w = f2h(acc[mr][nc][3]);
        *(ushort4*)&C[(size_t)row * 512 + col] = o;
      }
    }
  }
}

// ---------------------------------------------------------------------------
// prep: f32->f16 convert of x, Wt1/Wt2 build (transpose+cvt), dst histogram
// ---------------------------------------------------------------------------
__global__ void prep(const float* __restrict__ x, const float* __restrict__ W1l,
                     const float* __restrict__ W1r, const float* __restrict__ W2l,
                     const float* __restrict__ W2r, const int* __restrict__ ei,
                     unsigned short* __restrict__ xh, unsigned short* __restrict__ Wt1,
                     unsigned short* __restrict__ Wt2, int* __restrict__ cnt,
                     int n4x, int Etot, int E) {
  int t = blockIdx.x * 256 + threadIdx.x;
  if (t < n4x) {
    float4 v = *(const float4*)&x[(size_t)t * 4];
    ushort4 o;
    o.x = f2h(v.x); o.y = f2h(v.y); o.z = f2h(v.z); o.w = f2h(v.w);
    *(ushort4*)&xh[(size_t)t * 4] = o;
    return;
  }
  t -= n4x;
  if (t < 131072) {
    int n = t >> 8, k = t & 255;
    const float* W = (n < 256) ? W1l : W1r;
    Wt1[t] = f2h(W[k * 256 + (n & 255)]);
    return;
  }
  t -= 131072;
  if (t < 131072) {
    int n = t >> 8, k = t & 255;
    const float* W = (n < 256) ? W2l : W2r;
    Wt2[t] = f2h(W[k * 256 + (n & 255)]);
    return;
  }
  t -= 131072;
  if (t < Etot) {
    int d = (t < E) ? ei[E + t] : t - E;
    atomicAdd(&cnt[d], 1);
  }
}

// ---------------------------------------------------------------------------
// hierarchical exclusive scan of cnt[N] -> rowptr[N]
// ---------------------------------------------------------------------------
__global__ __launch_bounds__(256) void scan_partial(const int* __restrict__ cnt,
                                                    int* __restrict__ bsum, int N) {
  __shared__ int red[256];
  int t = threadIdx.x;
  int i = blockIdx.x * 1024 + t * 4;
  int s = 0;
  if (i + 3 < N) {
    int4 v = *(const int4*)&cnt[i];
    s = v.x + v.y + v.z + v.w;
  } else {
    for (int k = 0; k < 4; ++k)
      if (i + k < N) s += cnt[i + k];
  }
  red[t] = s;
  __syncthreads();
  for (int off = 128; off > 0; off >>= 1) {
    if (t < off) red[t] += red[t + off];
    __syncthreads();
  }
  if (t == 0) bsum[blockIdx.x] = red[0];
}

__global__ void scan_bsums(const int* __restrict__ bsum, int* __restrict__ boff,
                           int* __restrict__ rowptr, int nb, int N, int Etot) {
  int t = threadIdx.x;  // 64
  int v = (t < nb) ? bsum[t] : 0;
  int x = v;
  for (int off = 1; off < 64; off <<= 1) {
    int y = __shfl_up(x, off);
    if (t >= off) x += y;
  }
  if (t < nb) boff[t] = x - v;  // exclusive
  if (t == 0) rowptr[N] = Etot;
}

__global__ __launch_bounds__(256) void scan_final(int* __restrict__ cnt,
                                                  const int* __restrict__ boff,
                                                  int* __restrict__ rowptr, int N) {
  __shared__ int red[256];
  int t = threadIdx.x;
  int i = blockIdx.x * 1024 + t * 4;
  int c0 = 0, c1 = 0, c2 = 0, c3 = 0;
  if (i + 3 < N) {
    int4 v = *(const int4*)&cnt[i];
    c0 = v.x; c1 = v.y; c2 = v.z; c3 = v.w;
    *(int4*)&cnt[i] = make_int4(0, 0, 0, 0);  // reset for scatter pass
  } else {
    if (i + 0 < N) { c0 = cnt[i + 0]; cnt[i + 0] = 0; }
    if (i + 1 < N) { c1 = cnt[i + 1]; cnt[i + 1] = 0; }
    if (i + 2 < N) { c2 = cnt[i + 2]; cnt[i + 2] = 0; }
    if (i + 3 < N) { c3 = cnt[i + 3]; cnt[i + 3] = 0; }
  }
  int s = c0 + c1 + c2 + c3;
  red[t] = s;
  __syncthreads();
  for (int off = 1; off < 256; off <<= 1) {
    int y = (t >= off) ? red[t - off] : 0;
    __syncthreads();
    red[t] += y;
    __syncthreads();
  }
  int excl = red[t] - s + boff[blockIdx.x];
  if (i + 3 < N) {
    *(int4*)&rowptr[i] = make_int4(excl, excl + c0, excl + c0 + c1, excl + c0 + c1 + c2);
  } else {
    if (i + 0 < N) rowptr[i + 0] = excl;
    if (i + 1 < N) rowptr[i + 1] = excl + c0;
    if (i + 2 < N) rowptr[i + 2] = excl + c0 + c1;
    if (i + 3 < N) rowptr[i + 3] = excl + c0 + c1 + c2;
  }
}

__global__ void scatter_src(const int* __restrict__ ei, const int* __restrict__ rowptr,
                            int* __restrict__ cur, int* __restrict__ srcs,
                            int Etot, int E) {
  int e = blockIdx.x * 256 + threadIdx.x;
  if (e >= Etot) return;
  int s, d;
  if (e < E) { s = ei[e]; d = ei[E + e]; } else { s = e - E; d = s; }
  int pos = rowptr[d] + atomicAdd(&cur[d], 1);
  srcs[pos] = s;
}

// ---------------------------------------------------------------------------
// Fused GATv2: one wave per dst, 2 edges/iteration (32 lanes each), raw-exp
// softmax, 16B/lane f16 gathers, 4-buf (8-edge-in-flight) prefetch pipeline.
// lane = half*32+sub; sub owns ch sub*8..+7 (head = sub>>3, 8 lanes/head).
// leaky_relu(x) = 0.6x + 0.4|x|;  score = e.(0.6w) + |e|.(0.4w)
// ---------------------------------------------------------------------------
template <int CONCAT>
__global__ __launch_bounds__(256) void gat_fused(const unsigned short* __restrict__ xlr,
                                                 const float* __restrict__ att,
                                                 const float* __restrict__ bias,
                                                 const int* __restrict__ rowptr,
                                                 const int* __restrict__ srcs,
                                                 void* __restrict__ outv, int N) {
  int d = (blockIdx.x << 2) + (threadIdx.x >> 6);
  if (d >= N) return;
  int lane = threadIdx.x & 63;
  int half = lane >> 5, sub = lane & 31;
  uint4 ub = *(const uint4*)&xlr[(size_t)d * 512 + 256 + sub * 8];
  h2 xb0 = bch(ub.x), xb1 = bch(ub.y), xb2 = bch(ub.z), xb3 = bch(ub.w);
  float4 wa = *(const float4*)&att[sub * 8];
  float4 wb = *(const float4*)&att[sub * 8 + 4];
  h2 w060 = {(_Float16)(0.6f * wa.x), (_Float16)(0.6f * wa.y)};
  h2 w061 = {(_Float16)(0.6f * wa.z), (_Float16)(0.6f * wa.w)};
  h2 w062 = {(_Float16)(0.6f * wb.x), (_Float16)(0.6f * wb.y)};
  h2 w063 = {(_Float16)(0.6f * wb.z), (_Float16)(0.6f * wb.w)};
  h2 w040 = {(_Float16)(0.4f * wa.x), (_Float16)(0.4f * wa.y)};
  h2 w041 = {(_Float16)(0.4f * wa.z), (_Float16)(0.4f * wa.w)};
  h2 w042 = {(_Float16)(0.4f * wb.x), (_Float16)(0.4f * wb.y)};
  h2 w043 = {(_Float16)(0.4f * wb.z), (_Float16)(0.4f * wb.w)};
  int i0 = rowptr[d], end = rowptr[d + 1];
  int eM1 = end - 1;
  float den = 0.f;
  float acc[8] = {};

  auto GLD = [&](int e) -> uint4 {
    int j = min(e + half, eM1);
    return *(const uint4*)&xlr[(size_t)srcs[j] * 512 + sub * 8];
  };
  auto PROC = [&](uint4 c, bool valid) {
    h2 c0 = bch(c.x), c1 = bch(c.y), c2 = bch(c.z), c3 = bch(c.w);
    h2 e0 = c0 + xb0, e1 = c1 + xb1, e2 = c2 + xb2, e3 = c3 + xb3;
    float p;
#ifdef HAVE_FDOT2
    h2 a0 = bch(h2u(e0) & 0x7FFF7FFFu);
    h2 a1 = bch(h2u(e1) & 0x7FFF7FFFu);
    h2 a2 = bch(h2u(e2) & 0x7FFF7FFFu);
    h2 a3 = bch(h2u(e3) & 0x7FFF7FFFu);
    p = __builtin_amdgcn_fdot2(a0, w040,
        __builtin_amdgcn_fdot2(a1, w041,
        __builtin_amdgcn_fdot2(a2, w042,
        __builtin_amdgcn_fdot2(a3, w043,
        __builtin_amdgcn_fdot2(e0, w060,
        __builtin_amdgcn_fdot2(e1, w061,
        __builtin_amdgcn_fdot2(e2, w062,
        __builtin_amdgcn_fdot2(e3, w063, 0.f, false), false), false), false),
        false), false), false), false);
#else
    {
      float f0 = (float)e0.x, f1 = (float)e0.y, f2 = (float)e1.x, f3 = (float)e1.y;
      float f4 = (float)e2.x, f5 = (float)e2.y, f6 = (float)e3.x, f7 = (float)e3.y;
      float l0 = fmaxf(f0, 0.2f * f0), l1 = fmaxf(f1, 0.2f * f1);
      float l2 = fmaxf(f2, 0.2f * f2), l3 = fmaxf(f3, 0.2f * f3);
      float l4 = fmaxf(f4, 0.2f * f4), l5 = fmaxf(f5, 0.2f * f5);
      float l6 = fmaxf(f6, 0.2f * f6), l7 = fmaxf(f7, 0.2f * f7);
      p = l0 * wa.x + l1 * wa.y + l2 * wa.z + l3 * wa.w +
          l4 * wb.x + l5 * wb.y + l6 * wb.z + l7 * wb.w;
    }
#endif
    p += __shfl_xor(p, 1);
    p += __shfl_xor(p, 2);
    p += __shfl_xor(p, 4);   // all 8 lanes of the head group hold the score
    float ex = valid ? __expf(p) : 0.f;
    den += ex;
    acc[0] = fmaf(ex, (float)c0.x, acc[0]);
    acc[1] = fmaf(ex, (float)c0.y, acc[1]);
    acc[2] = fmaf(ex, (float)c1.x, acc[2]);
    acc[3] = fmaf(ex, (float)c1.y, acc[3]);
    acc[4] = fmaf(ex, (float)c2.x, acc[4]);
    acc[5] = fmaf(ex, (float)c2.y, acc[5]);
    acc[6] = fmaf(ex, (float)c3.x, acc[6]);
    acc[7] = fmaf(ex, (float)c3.y, acc[7]);
  };

  // 4 buffers x 2 edges = 8 edges in flight (MLP; gather-latency hiding)
  uint4 b0 = GLD(i0), b1 = GLD(i0 + 2), b2 = GLD(i0 + 4), b3 = GLD(i0 + 6);
  for (int i = i0; i < end; i += 2) {
    uint4 c = b0;
    b0 = b1; b1 = b2; b2 = b3;
    b3 = GLD(i + 8);
    PROC(c, (i + half) < end);
  }
  // merge the two edge-halves
  den += __shfl_xor(den, 32);
#pragma unroll
  for (int k = 0; k < 8; ++k) acc[k] += __shfl_xor(acc[k], 32);
  float inv = 1.f / den;
  if (CONCAT) {
    if (half == 0) {
      float4 ba = *(const float4*)&bias[sub * 8];
      float4 bb2 = *(const float4*)&bias[sub * 8 + 4];
      uint4 o;
      o.x = (unsigned)f2h(fmaf(acc[0], inv, ba.x)) | ((unsigned)f2h(fmaf(acc[1], inv, ba.y)) << 16);
      o.y = (unsigned)f2h(fmaf(acc[2], inv, ba.z)) | ((unsigned)f2h(fmaf(acc[3], inv, ba.w)) << 16);
      o.z = (unsigned)f2h(fmaf(acc[4], inv, bb2.x)) | ((unsigned)f2h(fmaf(acc[5], inv, bb2.y)) << 16);
      o.w = (unsigned)f2h(fmaf(acc[6], inv, bb2.z)) | ((unsigned)f2h(fmaf(acc[7], inv, bb2.w)) << 16);
      *(uint4*)&((unsigned short*)outv)[(size_t)d * 256 + sub * 8] = o;
    }
  } else {
    float v[8];
#pragma unroll
    for (int k = 0; k < 8; ++k) {
      v[k] = acc[k] * inv;
      v[k] += __shfl_xor(v[k], 8);
      v[k] += __shfl_xor(v[k], 16);  // sum over 4 heads
    }
    if (lane < 8) {  // half==0 && sub<8: ch sub*8..+7 of 64
      float4 ba = *(const float4*)&bias[sub * 8];
      float4 bb2 = *(const float4*)&bias[sub * 8 + 4];
      float* op = &((float*)outv)[(size_t)d * 64 + sub * 8];
      *(float4*)op = make_float4(0.25f * v[0] + ba.x, 0.25f * v[1] + ba.y,
                                 0.25f * v[2] + ba.z, 0.25f * v[3] + ba.w);
      *(float4*)(op + 4) = make_float4(0.25f * v[4] + bb2.x, 0.25f * v[5] + bb2.y,
                                       0.25f * v[6] + bb2.z, 0.25f * v[7] + bb2.w);
    }
  }
}

// column sums/sumsq over h[N,256] f16, LDS-reduced, 8 atomics per 64 lanes
__global__ __launch_bounds__(256) void bn_stats(const unsigned short* __restrict__ h,
                                                float* __restrict__ sums, int N) {
  __shared__ float4 rs[4][64], rq[4][64];
  int lane = threadIdx.x & 63;
  int rg = threadIdx.x >> 6;
  int c4 = lane * 4;
  float s0 = 0, s1 = 0, s2 = 0, s3 = 0, q0 = 0, q1 = 0, q2 = 0, q3 = 0;
  for (int r = blockIdx.x * 4 + rg; r < N; r += gridDim.x * 4) {
    uint2 v = *(const uint2*)&h[(size_t)r * 256 + c4];
    h2 a = bch(v.x), b = bch(v.y);
    float f0 = (float)a.x, f1 = (float)a.y, f2 = (float)b.x, f3 = (float)b.y;
    s0 += f0; q0 += f0 * f0;
    s1 += f1; q1 += f1 * f1;
    s2 += f2; q2 += f2 * f2;
    s3 += f3; q3 += f3 * f3;
  }
  rs[rg][lane] = make_float4(s0, s1, s2, s3);
  rq[rg][lane] = make_float4(q0, q1, q2, q3);
  __syncthreads();
  if (rg == 0) {
    float4 S = rs[0][lane], Q = rq[0][lane];
#pragma unroll
    for (int g = 1; g < 4; ++g) {
      float4 t = rs[g][lane]; S.x += t.x; S.y += t.y; S.z += t.z; S.w += t.w;
      float4 u = rq[g][lane]; Q.x += u.x; Q.y += u.y; Q.z += u.z; Q.w += u.w;
    }
    atomicAdd(&sums[c4 + 0], S.x); atomicAdd(&sums[c4 + 1], S.y);
    atomicAdd(&sums[c4 + 2], S.z); atomicAdd(&sums[c4 + 3], S.w);
    atomicAdd(&sums[256 + c4 + 0], Q.x); atomicAdd(&sums[256 + c4 + 1], Q.y);
    atomicAdd(&sums[256 + c4 + 2], Q.z); atomicAdd(&sums[256 + c4 + 3], Q.w);
  }
}

// h = relu(h*scale+shift), f16 in-place, 8 elems/thread; coef computed inline
__global__ void bn_apply_relu(unsigned short* __restrict__ h, const float* __restrict__ sums,
                              const float* __restrict__ g, const float* __restrict__ be,
                              int N) {
  int i = blockIdx.x * 256 + threadIdx.x;
  if (i >= N * 32) return;
  int base = i * 8, c = base & 255;
  float inv_n = 1.f / (float)N;
  float4 sm0 = *(const float4*)&sums[c],      sm1 = *(const float4*)&sums[c + 4];
  float4 qm0 = *(const float4*)&sums[256 + c], qm1 = *(const float4*)&sums[256 + c + 4];
  float4 gg0 = *(const float4*)&g[c],  gg1 = *(const float4*)&g[c + 4];
  float4 bb0 = *(const float4*)&be[c], bb1 = *(const float4*)&be[c + 4];
  float sc[8], sh[8];
  float mus[8] = {sm0.x * inv_n, sm0.y * inv_n, sm0.z * inv_n, sm0.w * inv_n,
                  sm1.x * inv_n, sm1.y * inv_n, sm1.z * inv_n, sm1.w * inv_n};
  float qs[8] = {qm0.x * inv_n, qm0.y * inv_n, qm0.z * inv_n, qm0.w * inv_n,
                 qm1.x * inv_n, qm1.y * inv_n, qm1.z * inv_n, qm1.w * inv_n};
  float gv[8] = {gg0.x, gg0.y, gg0.z, gg0.w, gg1.x, gg1.y, gg1.z, gg1.w};
  float bv[8] = {bb0.x, bb0.y, bb0.z, bb0.w, bb1.x, bb1.y, bb1.z, bb1.w};
#pragma unroll
  for (int k = 0; k < 8; ++k) {
    sc[k] = gv[k] * rsqrtf(qs[k] - mus[k] * mus[k] + EPSBN);
    sh[k] = bv[k] - mus[k] * sc[k];
  }
  uint4 v = *(const uint4*)&h[base];
  h2 p0 = bch(v.x), p1 = bch(v.y), p2 = bch(v.z), p3 = bch(v.w);
  float r[8];
  r[0] = fmaf((float)p0.x, sc[0], sh[0]);
  r[1] = fmaf((float)p0.y, sc[1], sh[1]);
  r[2] = fmaf((float)p1.x, sc[2], sh[2]);
  r[3] = fmaf((float)p1.y, sc[3], sh[3]);
  r[4] = fmaf((float)p2.x, sc[4], sh[4]);
  r[5] = fmaf((float)p2.y, sc[5], sh[5]);
  r[6] = fmaf((float)p3.x, sc[6], sh[6]);
  r[7] = fmaf((float)p3.y, sc[7], sh[7]);
#pragma unroll
  for (int k = 0; k < 8; ++k) r[k] = r[k] > 0.f ? r[k] : 0.f;
  uint4 o;
  o.x = (unsigned)f2h(r[0]) | ((unsigned)f2h(r[1]) << 16);
  o.y = (unsigned)f2h(r[2]) | ((unsigned)f2h(r[3]) << 16);
  o.z = (unsigned)f2h(r[4]) | ((unsigned)f2h(r[5]) << 16);
  o.w = (unsigned)f2h(r[6]) | ((unsigned)f2h(r[7]) << 16);
  *(uint4*)&h[base] = o;
}

// column stats over o[:, :32], coalesced float4 reads + LDS reduce
__global__ __launch_bounds__(256) void bn2_stats(const float* __restrict__ o,
                                                 float* __restrict__ sums, int N) {
  __shared__ float4 lsum[256], lqum[256];
  int t = threadIdx.x;
  int q = t & 7, rs = t >> 3;  // colquad 0..7, row-slot 0..31
  float4 S = {0, 0, 0, 0}, Q = {0, 0, 0, 0};
  for (int r = blockIdx.x * 32 + rs; r < N; r += gridDim.x * 32) {
    float4 v = *(const float4*)&o[(size_t)r * 64 + q * 4];
    S.x += v.x; Q.x += v.x * v.x;
    S.y += v.y; Q.y += v.y * v.y;
    S.z += v.z; Q.z += v.z * v.z;
    S.w += v.w; Q.w += v.w * v.w;
  }
  lsum[t] = S; lqum[t] = Q;
  __syncthreads();
  if (t < 8) {
    float4 Sa = lsum[t], Qa = lqum[t];
    for (int k = 1; k < 32; ++k) {
      float4 a = lsum[t + 8 * k], b = lqum[t + 8 * k];
      Sa.x += a.x; Sa.y += a.y; Sa.z += a.z; Sa.w += a.w;
      Qa.x += b.x; Qa.y += b.y; Qa.z += b.z; Qa.w += b.w;
    }
    atomicAdd(&sums[t * 4 + 0], Sa.x); atomicAdd(&sums[t * 4 + 1], Sa.y);
    atomicAdd(&sums[t * 4 + 2], Sa.z); atomicAdd(&sums[t * 4 + 3], Sa.w);
    atomicAdd(&sums[32 + t * 4 + 0], Qa.x); atomicAdd(&sums[32 + t * 4 + 1], Qa.y);
    atomicAdd(&sums[32 + t * 4 + 2], Qa.z); atomicAdd(&sums[32 + t * 4 + 3], Qa.w);
  }
}

// row-parallel: lanes 0-31 -> z_mu, lanes 32-63 -> sigmoid. Coalesced reads.
__global__ void write_out(const float* __restrict__ o, const float* __restrict__ sums,
                          float* __restrict__ out, int N) {
  int t = threadIdx.x;
  int n = blockIdx.x * 4 + (t >> 6);
  if (n >= N) return;
  int lane = t & 63;
  float v = o[(size_t)n * 64 + lane];
  if (lane < 32) {
    float inv_n = 1.f / (float)N;
    float mu = sums[lane] * inv_n;
    float var = sums[32 + lane] * inv_n - mu * mu;
    out[(size_t)n * 32 + lane] = (v - mu) * rsqrtf(var + EPSBN);
  } else {
    out[(size_t)N * 32 + (size_t)n * 32 + (lane - 32)] = 1.f / (1.f + __expf(-v));
  }
}

extern "C" void kernel_launch(void* const* d_in, const int* in_sizes, int n_in,
                              void* d_out, int out_size, void* d_ws, size_t ws_size,
                              hipStream_t stream) {
  const float* x    = (const float*)d_in[0];
  const int*   ei   = (const int*)d_in[1];
  const float* W1l  = (const float*)d_in[2];
  const float* W1r  = (const float*)d_in[3];
  const float* att1 = (const float*)d_in[4];
  const float* b1   = (const float*)d_in[5];
  const float* g1   = (const float*)d_in[6];
  const float* be1  = (const float*)d_in[7];
  const float* W2l  = (const float*)d_in[8];
  const float* W2r  = (const float*)d_in[9];
  const float* att2 = (const float*)d_in[10];
  const float* b2   = (const float*)d_in[11];
  float* out = (float*)d_out;

  const int N = in_sizes[0] / 256;   // 50000
  const int E = in_sizes[1] / 2;     // 800000
  const int Etot = E + N;
  const int Npad = ((N + 127) / 128) * 128;
  const int nb = (N + 1023) / 1024;  // scan chunks

  char* ws = (char*)d_ws;
  unsigned short* xh  = (unsigned short*)ws; ws += (size_t)Npad * 256 * 2;  // x f16
  unsigned short* hb  = (unsigned short*)ws; ws += (size_t)Npad * 256 * 2;  // h1 f16
  unsigned short* AB  = (unsigned short*)ws; ws += (size_t)Npad * 512 * 2;  // [xl|xr] f16
  unsigned short* Wt1 = (unsigned short*)ws; ws += (size_t)512 * 256 * 2;
  unsigned short* Wt2 = (unsigned short*)ws; ws += (size_t)512 * 256 * 2;
  float* o    = (float*)ws;  ws += (size_t)N * 64 * 4;
  int* rowptr = (int*)ws;    ws += (size_t)(N + 1) * 4;
  int* cnt    = (int*)ws;    ws += (size_t)N * 4;
  int* srcs   = (int*)ws;    ws += (size_t)Etot * 4;
  int* bsum   = (int*)ws;    ws += 64 * 4;
  int* boff   = (int*)ws;    ws += 64 * 4;
  float* sums1 = (float*)ws; ws += 512 * 4;
  float* sums2 = (float*)ws; ws += 64 * 4;

  dim3 gemmGrid(Npad / 128, 4);
  int dstBlocks = (N + 3) / 4;
  int n4x = N * 64;
  int prepTotal = n4x + 131072 + 131072 + Etot;

  hipMemsetAsync(cnt, 0, (size_t)N * 4, stream);
  hipMemsetAsync(sums1, 0, 512 * 4, stream);
  hipMemsetAsync(sums2, 0, 64 * 4, stream);
  prep<<<(prepTotal + 255) / 256, 256, 0, stream>>>(x, W1l, W1r, W2l, W2r, ei,
                                                    xh, Wt1, Wt2, cnt, n4x, Etot, E);
  scan_partial<<<nb, 256, 0, stream>>>(cnt, bsum, N);
  scan_bsums<<<1, 64, 0, stream>>>(bsum, boff, rowptr, nb, N, Etot);
  scan_final<<<nb, 256, 0, stream>>>(cnt, boff, rowptr, N);  // also zeroes cnt
  scatter_src<<<(Etot + 255) / 256, 256, 0, stream>>>(ei, rowptr, cnt, srcs, Etot, E);

  // ---- conv1 ----
  gemm_dual<<<gemmGrid, 256, 0, stream>>>(xh, Wt1, AB, N);
  gat_fused<1><<<dstBlocks, 256, 0, stream>>>(AB, att1, b1, rowptr, srcs, hb, N);
  bn_stats<<<512, 256, 0, stream>>>(hb, sums1, N);
  bn_apply_relu<<<(N * 32 + 255) / 256, 256, 0, stream>>>(hb, sums1, g1, be1, N);

  // ---- conv2 ----
  gemm_dual<<<gemmGrid, 256, 0, stream>>>(hb, Wt2, AB, N);
  gat_fused<0><<<dstBlocks, 256, 0, stream>>>(AB, att2, b2, rowptr, srcs, o, N);
  bn2_stats<<<128, 256, 0, stream>>>(o, sums2, N);
  write_out<<<dstBlocks, 256, 0, stream>>>(o, sums2, out, N);
}